// Round 6
// baseline (226.544 us; speedup 1.0000x reference)
//
#include <hip/hip_runtime.h>

// Problem constants (fixed by setup_inputs)
#define DIM 512
#define NQ 64
#define BATCH 2048

typedef __bf16  bf16x8  __attribute__((ext_vector_type(8)));
typedef float   floatx4 __attribute__((ext_vector_type(4)));

static __device__ inline unsigned short f2bf(float f) {
    unsigned int u = __float_as_uint(f);
    return (unsigned short)((u + 0x7fffu + ((u >> 16) & 1u)) >> 16);  // RNE
}
static __device__ inline float bf2f(unsigned short h) {
    return __uint_as_float((unsigned int)h << 16);
}
static __device__ inline unsigned int pack2(float a, float b) {
    return (unsigned)f2bf(a) | ((unsigned)f2bf(b) << 16);
}

// Pack points fp32 (2048,512) -> bf16 Pb (2 MB, L2-resident for the GEMM)
__global__ void hsq_pack_kernel(const float* __restrict__ pts,
                                unsigned short* __restrict__ Pb) {
    const int i8 = blockIdx.x * 256 + threadIdx.x;
    const float4 v1 = *(const float4*)(pts + (size_t)i8 * 8);
    const float4 v2 = *(const float4*)(pts + (size_t)i8 * 8 + 4);
    uint4 wv;
    wv.x = pack2(v1.x, v1.y); wv.y = pack2(v1.z, v1.w);
    wv.z = pack2(v2.x, v2.y); wv.w = pack2(v2.z, v2.w);
    *(uint4*)(Pb + (size_t)i8 * 8) = wv;
}

// Expand q_coefs (n_mono,64) -> W[k][e][d] (bf16, d contiguous). norm2 partials
// as plain per-block stores (no atomics — 64-lane atomicAdd on 2 cache lines
// serialized ~65K RMWs and cost ~110 us in rounds 3-4).
__global__ __launch_bounds__(256, 4)
void hsq_expand_kernel(const float* __restrict__ qc,
                       unsigned short* __restrict__ W,
                       float* __restrict__ npart) {
    const int e    = blockIdx.x;          // 0..511
    const int dblk = blockIdx.y;          // 0..3
    const int pb   = blockIdx.y * 512 + blockIdx.x;   // 0..2047
    const int wid  = threadIdx.x >> 6;
    const int k    = threadIdx.x & 63;    // lane = quadric index
    const int d0   = dblk * 128 + wid * 32;

    __shared__ unsigned short tv[64 * 136];
    __shared__ float part[4][64];

    float v[32];
#pragma unroll
    for (int s = 0; s < 32; ++s) {
        const int d = d0 + s;
        const int i = d < e ? d : e;
        const int j = d < e ? e : d;
        const int idx = i * DIM - ((i * (i - 1)) >> 1) + (j - i);
        v[s] = qc[(size_t)idx * NQ + k];
    }

    float nacc = 0.0f;
#pragma unroll
    for (int s = 0; s < 32; ++s)
        if (d0 + s >= e) nacc += v[s] * v[s];

#pragma unroll
    for (int t = 0; t < 4; ++t) {
        float sc[8];
#pragma unroll
        for (int q = 0; q < 8; ++q) {
            const int d = d0 + t * 8 + q;
            sc[q] = v[t * 8 + q] * ((d == e) ? 2.0f : 1.41421356237309515f);
        }
        uint4 w;
        w.x = pack2(sc[0], sc[1]); w.y = pack2(sc[2], sc[3]);
        w.z = pack2(sc[4], sc[5]); w.w = pack2(sc[6], sc[7]);
        *(uint4*)&tv[k * 136 + wid * 32 + t * 8] = w;
    }
    part[wid][k] = nacc;
    __syncthreads();

#pragma unroll
    for (int r = 0; r < 4; ++r) {
        const int kk = r * 16 + (threadIdx.x >> 4);
        const int u  = threadIdx.x & 15;
        const uint4 w = *(const uint4*)&tv[kk * 136 + u * 8];
        *(uint4*)(W + ((size_t)(kk * DIM + e)) * DIM + dblk * 128 + u * 8) = w;
    }
    if (threadIdx.x < 64) {
        npart[(size_t)k * 2048 + pb] =
            part[0][k] + part[1][k] + part[2][k] + part[3][k];
    }
}

// m97-style GEMM, BK=32: 128(m) x 128(n = one k's 128-e range), A+B double-
// buffered via global_load_lds(16B). LDS ~35 KB -> 4 blocks/CU (16 waves/CU,
// vs 2 blocks at BK=64 — occupancy is the lever per m97's ladder).
// Swizzle: LDS slot = chunk ^ ((row>>1)&3), applied on the global-source side,
// so staging stays lane-contiguous and ds_read_b128 is conflict-free (<=2-way).
__global__ __launch_bounds__(256, 4)
void hsq_gemm_kernel(const unsigned short* __restrict__ Pb,
                     const unsigned short* __restrict__ W,
                     const float* __restrict__ l_coefs,
                     float2* __restrict__ part) {
    // XCD swizzle: each XCD owns 8 k's; concurrent W set = one 512 KB slab.
    const int bid = blockIdx.x;
    const int xcd = bid & 7;
    const int loc = bid >> 3;                 // 0..511
    const int k   = xcd * 8 + (loc >> 6);     // 0..63
    const int rem = loc & 63;
    const int eb  = rem >> 4;                 // 0..3 (e-range of 128)
    const int m0  = (rem & 15) * 128;         // batch-tile base

    const int tid   = threadIdx.x;
    const int w     = tid >> 6;
    const int lane  = tid & 63;
    const int mhalf = w >> 1, nhalf = w & 1;
    const int c     = lane & 15;              // MFMA col
    const int quad  = lane >> 4;              // MFMA k-chunk / D row-block

    __shared__ unsigned short Ab[2][128 * 32];   // 2 x 8 KB
    __shared__ unsigned short Bb[2][128 * 32];   // 2 x 8 KB
    __shared__ float red[2][128][2];             // 2 KB

    const unsigned short* Wk = W + (size_t)k * DIM * DIM + (size_t)eb * 128 * DIM;

#define STAGE(buf_, it_) do {                                                   \
    const int lr_  = lane >> 2;                                                 \
    const int gch_ = (lane & 3) ^ ((lane >> 3) & 3);                            \
    _Pragma("unroll")                                                           \
    for (int i_ = 0; i_ < 2; ++i_) {                                            \
        const int rb_  = w * 32 + i_ * 16;                                      \
        const int row_ = rb_ + lr_;                                             \
        __builtin_amdgcn_global_load_lds(                                       \
            (const __attribute__((address_space(1))) unsigned int*)             \
                (Pb + (size_t)(m0 + row_) * DIM + (it_) * 32 + gch_ * 8),       \
            (__attribute__((address_space(3))) unsigned int*)                   \
                &Ab[buf_][rb_ * 32], 16, 0, 0);                                 \
        __builtin_amdgcn_global_load_lds(                                       \
            (const __attribute__((address_space(1))) unsigned int*)             \
                (Wk + (size_t)row_ * DIM + (it_) * 32 + gch_ * 8),              \
            (__attribute__((address_space(3))) unsigned int*)                   \
                &Bb[buf_][rb_ * 32], 16, 0, 0);                                 \
    }                                                                           \
} while (0)

    floatx4 acc[4][4];
#pragma unroll
    for (int mt = 0; mt < 4; ++mt)
#pragma unroll
        for (int nt = 0; nt < 4; ++nt)
            acc[mt][nt] = (floatx4){0.f, 0.f, 0.f, 0.f};

    float lcv[4];
#pragma unroll
    for (int nt = 0; nt < 4; ++nt)
        lcv[nt] = l_coefs[(eb * 128 + nhalf * 64 + nt * 16 + c) * NQ + k];

    // harvested p, packed 2 bf16 per VGPR: pf[mt][r][hi] covers nt {2hi, 2hi+1}
    unsigned int pf[4][4][2];
    const int hit_a = 4 * eb + 2 * nhalf;   // A-slab iter covering nt 0,1
    const int hit_b = hit_a + 1;            // covering nt 2,3

    STAGE(0, 0);
    __syncthreads();

#pragma unroll 2
    for (int it = 0; it < 16; ++it) {
        const int buf = it & 1;
        if (it < 15) STAGE(buf ^ 1, it + 1);

        if (it == hit_a || it == hit_b) {   // wave-uniform branch
            const int hi = (it == hit_b);
            const int c7 = c & 7, ch0 = c >> 3;
#pragma unroll
            for (int mt = 0; mt < 4; ++mt)
#pragma unroll
                for (int r = 0; r < 4; ++r) {
                    const int row = mhalf * 64 + mt * 16 + quad * 4 + r;
                    const int sw  = (row >> 1) & 3;
                    const unsigned short u0 = Ab[buf][row * 32 + ((ch0 ^ sw)) * 8 + c7];
                    const unsigned short u1 = Ab[buf][row * 32 + (((2 | ch0) ^ sw)) * 8 + c7];
                    pf[mt][r][hi] = (unsigned)u0 | ((unsigned)u1 << 16);
                }
        }

        bf16x8 af[4], bfr[4];
#pragma unroll
        for (int mt = 0; mt < 4; ++mt) {
            const int row  = mhalf * 64 + mt * 16 + c;
            const int slot = quad ^ ((row >> 1) & 3);
            af[mt] = *(const bf16x8*)&Ab[buf][row * 32 + slot * 8];
        }
#pragma unroll
        for (int nt = 0; nt < 4; ++nt) {
            const int er   = nhalf * 64 + nt * 16 + c;
            const int slot = quad ^ ((er >> 1) & 3);
            bfr[nt] = *(const bf16x8*)&Bb[buf][er * 32 + slot * 8];
        }
#pragma unroll
        for (int mt = 0; mt < 4; ++mt)
#pragma unroll
            for (int nt = 0; nt < 4; ++nt)
                acc[mt][nt] = __builtin_amdgcn_mfma_f32_16x16x32_bf16(
                    af[mt], bfr[nt], acc[mt][nt], 0, 0, 0);
        __syncthreads();
    }
#undef STAGE

    // ---- Epilogue: pv = sum_e p*(0.5g+l), pg = sum_e (g+l)^2 over this eb ----
#pragma unroll
    for (int mt = 0; mt < 4; ++mt)
#pragma unroll
        for (int r = 0; r < 4; ++r) {
            const float p0 = bf2f((unsigned short)(pf[mt][r][0] & 0xffff));
            const float p1 = bf2f((unsigned short)(pf[mt][r][0] >> 16));
            const float p2 = bf2f((unsigned short)(pf[mt][r][1] & 0xffff));
            const float p3 = bf2f((unsigned short)(pf[mt][r][1] >> 16));
            const float pp[4] = {p0, p1, p2, p3};
            float pv = 0.f, pg = 0.f;
#pragma unroll
            for (int nt = 0; nt < 4; ++nt) {
                const float g = acc[mt][nt][r];
                const float l = lcv[nt];
                pv += pp[nt] * (0.5f * g + l);
                const float gq = g + l;
                pg += gq * gq;
            }
#pragma unroll
            for (int off = 1; off < 16; off <<= 1) {
                pv += __shfl_xor(pv, off);
                pg += __shfl_xor(pg, off);
            }
            if (c == 0) {
                const int row = mhalf * 64 + mt * 16 + quad * 4 + r;
                red[nhalf][row][0] = pv;
                red[nhalf][row][1] = pg;
            }
        }
    __syncthreads();

    if (tid < 128) {
        const float pv = red[0][tid][0] + red[1][tid][0];
        const float pg = red[0][tid][1] + red[1][tid][1];
        part[((size_t)(eb * NQ + k)) * BATCH + m0 + tid] = make_float2(pv, pg);
    }
}

// Final: block per k. Reduces npart[k][*] -> norm2 in-block, then combines the
// 4 e-range partials into scores (coalesced reads).
__global__ void hsq_final_kernel(const float2* __restrict__ part,
                                 const float* __restrict__ npart,
                                 const float* __restrict__ free_coefs,
                                 float* __restrict__ out) {
    const int k = blockIdx.x;
    const int t = threadIdx.x;
    __shared__ float ws[4];

    const float4* src = (const float4*)(npart + (size_t)k * 2048);
    const float4 a = src[t * 2], b = src[t * 2 + 1];
    float s = a.x + a.y + a.z + a.w + b.x + b.y + b.z + b.w;
#pragma unroll
    for (int off = 1; off < 64; off <<= 1) s += __shfl_xor(s, off);
    if ((t & 63) == 0) ws[t >> 6] = s;
    __syncthreads();
    const float nrm = sqrtf(ws[0] + ws[1] + ws[2] + ws[3]);
    const float fc  = free_coefs[k];

#pragma unroll
    for (int i = 0; i < 8; ++i) {
        const int bidx = i * 256 + t;
        float pv = 0.f, pg = 0.f;
#pragma unroll
        for (int eb = 0; eb < 4; ++eb) {
            const float2 p = part[((size_t)(eb * NQ + k)) * BATCH + bidx];
            pv += p.x; pg += p.y;
        }
        const float vals = fabsf(pv + fc);
        out[(size_t)bidx * NQ + k] = (sqrtf(0.25f * pg + vals * nrm) - 0.5f * sqrtf(pg)) / nrm;
    }
}

extern "C" void kernel_launch(void* const* d_in, const int* in_sizes, int n_in,
                              void* d_out, int out_size, void* d_ws, size_t ws_size,
                              hipStream_t stream) {
    const float* points     = (const float*)d_in[0];  // (2048, 512)
    const float* q_coefs    = (const float*)d_in[1];  // (131328, 64)
    const float* l_coefs    = (const float*)d_in[2];  // (512, 64)
    const float* free_coefs = (const float*)d_in[3];  // (1, 64)
    float* out = (float*)d_out;                       // (2048, 64)

    char* ws = (char*)d_ws;
    unsigned short* W  = (unsigned short*)ws;                              // 32 MiB
    unsigned short* Pb = (unsigned short*)(ws + 33554432);                 // 2 MiB
    float2*         part  = (float2*)(ws + 35651584);                      // 4 MiB
    float*          npart = (float*)(ws + 39845888);                       // 512 KiB

    hsq_pack_kernel<<<dim3(BATCH * DIM / 8 / 256), 256, 0, stream>>>(points, Pb);
    hsq_expand_kernel<<<dim3(DIM, 4), 256, 0, stream>>>(q_coefs, W, npart);
    hsq_gemm_kernel<<<dim3(NQ * 64), 256, 0, stream>>>(Pb, W, l_coefs, part);
    hsq_final_kernel<<<dim3(NQ), 256, 0, stream>>>(part, npart, free_coefs, out);
}

// Round 7
// 220.999 us; speedup vs baseline: 1.0251x; 1.0251x over previous
//
#include <hip/hip_runtime.h>

// Problem constants (fixed by setup_inputs)
#define DIM 512
#define NQ 64
#define BATCH 2048

typedef __bf16  bf16x8  __attribute__((ext_vector_type(8)));
typedef float   floatx4 __attribute__((ext_vector_type(4)));

static __device__ inline unsigned short f2bf(float f) {
    unsigned int u = __float_as_uint(f);
    return (unsigned short)((u + 0x7fffu + ((u >> 16) & 1u)) >> 16);  // RNE
}
static __device__ inline float bf2f(unsigned short h) {
    return __uint_as_float((unsigned int)h << 16);
}
static __device__ inline unsigned int pack2(float a, float b) {
    return (unsigned)f2bf(a) | ((unsigned)f2bf(b) << 16);
}

// Pack points fp32 (2048,512) -> bf16 Pb (2 MB, L2-resident for the GEMM)
__global__ void hsq_pack_kernel(const float* __restrict__ pts,
                                unsigned short* __restrict__ Pb) {
    const int i8 = blockIdx.x * 256 + threadIdx.x;
    const float4 v1 = *(const float4*)(pts + (size_t)i8 * 8);
    const float4 v2 = *(const float4*)(pts + (size_t)i8 * 8 + 4);
    uint4 wv;
    wv.x = pack2(v1.x, v1.y); wv.y = pack2(v1.z, v1.w);
    wv.z = pack2(v2.x, v2.y); wv.w = pack2(v2.z, v2.w);
    *(uint4*)(Pb + (size_t)i8 * 8) = wv;
}

// Expand q_coefs (n_mono,64) -> W[k][e][d] (bf16, d contiguous). norm2 partials
// as plain per-block stores (no atomics — 64-lane atomicAdd on 2 cache lines
// serialized ~65K RMWs and cost ~110 us in rounds 3-4).
__global__ __launch_bounds__(256, 4)
void hsq_expand_kernel(const float* __restrict__ qc,
                       unsigned short* __restrict__ W,
                       float* __restrict__ npart) {
    const int e    = blockIdx.x;          // 0..511
    const int dblk = blockIdx.y;          // 0..3
    const int pb   = blockIdx.y * 512 + blockIdx.x;   // 0..2047
    const int wid  = threadIdx.x >> 6;
    const int k    = threadIdx.x & 63;    // lane = quadric index
    const int d0   = dblk * 128 + wid * 32;

    __shared__ unsigned short tv[64 * 136];
    __shared__ float part[4][64];

    float v[32];
#pragma unroll
    for (int s = 0; s < 32; ++s) {
        const int d = d0 + s;
        const int i = d < e ? d : e;
        const int j = d < e ? e : d;
        const int idx = i * DIM - ((i * (i - 1)) >> 1) + (j - i);
        v[s] = qc[(size_t)idx * NQ + k];
    }

    float nacc = 0.0f;
#pragma unroll
    for (int s = 0; s < 32; ++s)
        if (d0 + s >= e) nacc += v[s] * v[s];

#pragma unroll
    for (int t = 0; t < 4; ++t) {
        float sc[8];
#pragma unroll
        for (int q = 0; q < 8; ++q) {
            const int d = d0 + t * 8 + q;
            sc[q] = v[t * 8 + q] * ((d == e) ? 2.0f : 1.41421356237309515f);
        }
        uint4 w;
        w.x = pack2(sc[0], sc[1]); w.y = pack2(sc[2], sc[3]);
        w.z = pack2(sc[4], sc[5]); w.w = pack2(sc[6], sc[7]);
        *(uint4*)&tv[k * 136 + wid * 32 + t * 8] = w;
    }
    part[wid][k] = nacc;
    __syncthreads();

#pragma unroll
    for (int r = 0; r < 4; ++r) {
        const int kk = r * 16 + (threadIdx.x >> 4);
        const int u  = threadIdx.x & 15;
        const uint4 w = *(const uint4*)&tv[kk * 136 + u * 8];
        *(uint4*)(W + ((size_t)(kk * DIM + e)) * DIM + dblk * 128 + u * 8) = w;
    }
    if (threadIdx.x < 64) {
        npart[(size_t)k * 2048 + pb] =
            part[0][k] + part[1][k] + part[2][k] + part[3][k];
    }
}

// m97-style GEMM, BK=32, 4 blocks/CU. Round-6 lesson: the in-loop p-harvest
// (pf, 32 VGPRs) blew the 128-reg budget at 4 waves/SIMD -> 146 MB of scratch
// spills. This version drops the harvest; the epilogue reads p straight from
// Pb (L2-hot, 2 MB). Register budget: acc 64 + af/bfr 32 + addr ~15 < 128.
__global__ __launch_bounds__(256, 4)
void hsq_gemm_kernel(const unsigned short* __restrict__ Pb,
                     const unsigned short* __restrict__ W,
                     const float* __restrict__ l_coefs,
                     float2* __restrict__ part) {
    // XCD swizzle: each XCD owns 8 k's; concurrent W set ~= 1-2 slabs (<=1 MB).
    const int bid = blockIdx.x;
    const int xcd = bid & 7;
    const int loc = bid >> 3;                 // 0..511
    const int k   = xcd * 8 + (loc >> 6);     // 0..63
    const int rem = loc & 63;
    const int eb  = rem >> 4;                 // 0..3 (e-range of 128)
    const int m0  = (rem & 15) * 128;         // batch-tile base

    const int tid   = threadIdx.x;
    const int w     = tid >> 6;
    const int lane  = tid & 63;
    const int mhalf = w >> 1, nhalf = w & 1;
    const int c     = lane & 15;              // MFMA col
    const int quad  = lane >> 4;              // MFMA k-chunk / D row-block

    __shared__ unsigned short Ab[2][128 * 32];   // 2 x 8 KB
    __shared__ unsigned short Bb[2][128 * 32];   // 2 x 8 KB
    __shared__ float red[2][128][2];             // 2 KB

    const unsigned short* Wk = W + (size_t)k * DIM * DIM + (size_t)eb * 128 * DIM;

#define STAGE(buf_, it_) do {                                                   \
    const int lr_  = lane >> 2;                                                 \
    const int gch_ = (lane & 3) ^ ((lane >> 3) & 3);                            \
    _Pragma("unroll")                                                           \
    for (int i_ = 0; i_ < 2; ++i_) {                                            \
        const int rb_  = w * 32 + i_ * 16;                                      \
        const int row_ = rb_ + lr_;                                             \
        __builtin_amdgcn_global_load_lds(                                       \
            (const __attribute__((address_space(1))) unsigned int*)             \
                (Pb + (size_t)(m0 + row_) * DIM + (it_) * 32 + gch_ * 8),       \
            (__attribute__((address_space(3))) unsigned int*)                   \
                &Ab[buf_][rb_ * 32], 16, 0, 0);                                 \
        __builtin_amdgcn_global_load_lds(                                       \
            (const __attribute__((address_space(1))) unsigned int*)             \
                (Wk + (size_t)row_ * DIM + (it_) * 32 + gch_ * 8),              \
            (__attribute__((address_space(3))) unsigned int*)                   \
                &Bb[buf_][rb_ * 32], 16, 0, 0);                                 \
    }                                                                           \
} while (0)

    floatx4 acc[4][4];
#pragma unroll
    for (int mt = 0; mt < 4; ++mt)
#pragma unroll
        for (int nt = 0; nt < 4; ++nt)
            acc[mt][nt] = (floatx4){0.f, 0.f, 0.f, 0.f};

    float lcv[4];
#pragma unroll
    for (int nt = 0; nt < 4; ++nt)
        lcv[nt] = l_coefs[(eb * 128 + nhalf * 64 + nt * 16 + c) * NQ + k];

    STAGE(0, 0);
    __syncthreads();

    for (int it = 0; it < 16; ++it) {
        const int buf = it & 1;
        if (it < 15) STAGE(buf ^ 1, it + 1);

        bf16x8 af[4], bfr[4];
#pragma unroll
        for (int mt = 0; mt < 4; ++mt) {
            const int row  = mhalf * 64 + mt * 16 + c;
            const int slot = quad ^ ((row >> 1) & 3);
            af[mt] = *(const bf16x8*)&Ab[buf][row * 32 + slot * 8];
        }
#pragma unroll
        for (int nt = 0; nt < 4; ++nt) {
            const int er   = nhalf * 64 + nt * 16 + c;
            const int slot = quad ^ ((er >> 1) & 3);
            bfr[nt] = *(const bf16x8*)&Bb[buf][er * 32 + slot * 8];
        }
#pragma unroll
        for (int mt = 0; mt < 4; ++mt)
#pragma unroll
            for (int nt = 0; nt < 4; ++nt)
                acc[mt][nt] = __builtin_amdgcn_mfma_f32_16x16x32_bf16(
                    af[mt], bfr[nt], acc[mt][nt], 0, 0, 0);
        __syncthreads();
    }
#undef STAGE

    // ---- Epilogue: pv = sum_e p*(0.5g+l), pg = sum_e (g+l)^2 over this eb ----
    // p read from Pb (L2-hot): lane (c,quad) reads row m0+..+quad*4+r, col e(c,nt).
    const unsigned short* Pe = Pb + (size_t)(m0 + mhalf * 64) * DIM
                                  + eb * 128 + nhalf * 64 + c;
#pragma unroll
    for (int mt = 0; mt < 4; ++mt)
#pragma unroll
        for (int r = 0; r < 4; ++r) {
            const unsigned short* Prow = Pe + (size_t)(mt * 16 + quad * 4 + r) * DIM;
            float pv = 0.f, pg = 0.f;
#pragma unroll
            for (int nt = 0; nt < 4; ++nt) {
                const float g = acc[mt][nt][r];
                const float l = lcv[nt];
                pv += bf2f(Prow[nt * 16]) * (0.5f * g + l);
                const float gq = g + l;
                pg += gq * gq;
            }
#pragma unroll
            for (int off = 1; off < 16; off <<= 1) {
                pv += __shfl_xor(pv, off);
                pg += __shfl_xor(pg, off);
            }
            if (c == 0) {
                const int row = mhalf * 64 + mt * 16 + quad * 4 + r;
                red[nhalf][row][0] = pv;
                red[nhalf][row][1] = pg;
            }
        }
    __syncthreads();

    if (tid < 128) {
        const float pv = red[0][tid][0] + red[1][tid][0];
        const float pg = red[0][tid][1] + red[1][tid][1];
        part[((size_t)(eb * NQ + k)) * BATCH + m0 + tid] = make_float2(pv, pg);
    }
}

// Final: block per k. Reduces npart[k][*] -> norm2 in-block, then combines the
// 4 e-range partials into scores (coalesced reads).
__global__ void hsq_final_kernel(const float2* __restrict__ part,
                                 const float* __restrict__ npart,
                                 const float* __restrict__ free_coefs,
                                 float* __restrict__ out) {
    const int k = blockIdx.x;
    const int t = threadIdx.x;
    __shared__ float ws[4];

    const float4* src = (const float4*)(npart + (size_t)k * 2048);
    const float4 a = src[t * 2], b = src[t * 2 + 1];
    float s = a.x + a.y + a.z + a.w + b.x + b.y + b.z + b.w;
#pragma unroll
    for (int off = 1; off < 64; off <<= 1) s += __shfl_xor(s, off);
    if ((t & 63) == 0) ws[t >> 6] = s;
    __syncthreads();
    const float nrm = sqrtf(ws[0] + ws[1] + ws[2] + ws[3]);
    const float fc  = free_coefs[k];

#pragma unroll
    for (int i = 0; i < 8; ++i) {
        const int bidx = i * 256 + t;
        float pv = 0.f, pg = 0.f;
#pragma unroll
        for (int eb = 0; eb < 4; ++eb) {
            const float2 p = part[((size_t)(eb * NQ + k)) * BATCH + bidx];
            pv += p.x; pg += p.y;
        }
        const float vals = fabsf(pv + fc);
        out[(size_t)bidx * NQ + k] = (sqrtf(0.25f * pg + vals * nrm) - 0.5f * sqrtf(pg)) / nrm;
    }
}

extern "C" void kernel_launch(void* const* d_in, const int* in_sizes, int n_in,
                              void* d_out, int out_size, void* d_ws, size_t ws_size,
                              hipStream_t stream) {
    const float* points     = (const float*)d_in[0];  // (2048, 512)
    const float* q_coefs    = (const float*)d_in[1];  // (131328, 64)
    const float* l_coefs    = (const float*)d_in[2];  // (512, 64)
    const float* free_coefs = (const float*)d_in[3];  // (1, 64)
    float* out = (float*)d_out;                       // (2048, 64)

    char* ws = (char*)d_ws;
    unsigned short* W  = (unsigned short*)ws;                              // 32 MiB
    unsigned short* Pb = (unsigned short*)(ws + 33554432);                 // 2 MiB
    float2*         part  = (float2*)(ws + 35651584);                      // 4 MiB
    float*          npart = (float*)(ws + 39845888);                       // 512 KiB

    hsq_pack_kernel<<<dim3(BATCH * DIM / 8 / 256), 256, 0, stream>>>(points, Pb);
    hsq_expand_kernel<<<dim3(DIM, 4), 256, 0, stream>>>(q_coefs, W, npart);
    hsq_gemm_kernel<<<dim3(NQ * 64), 256, 0, stream>>>(Pb, W, l_coefs, part);
    hsq_final_kernel<<<dim3(NQ), 256, 0, stream>>>(part, npart, free_coefs, out);
}

// Round 8
// 204.760 us; speedup vs baseline: 1.1064x; 1.0793x over previous
//
#include <hip/hip_runtime.h>

// Problem constants (fixed by setup_inputs)
#define DIM 512
#define NQ 64
#define BATCH 2048

typedef __bf16  bf16x8  __attribute__((ext_vector_type(8)));
typedef float   floatx4 __attribute__((ext_vector_type(4)));

static __device__ inline unsigned short f2bf(float f) {
    unsigned int u = __float_as_uint(f);
    return (unsigned short)((u + 0x7fffu + ((u >> 16) & 1u)) >> 16);  // RNE
}
static __device__ inline float bf2f(unsigned short h) {
    return __uint_as_float((unsigned int)h << 16);
}
static __device__ inline unsigned int pack2(float a, float b) {
    return (unsigned)f2bf(a) | ((unsigned)f2bf(b) << 16);
}

// Pack points fp32 (2048,512) -> bf16 Pb (2 MB, L2-resident for the GEMM)
__global__ void hsq_pack_kernel(const float* __restrict__ pts,
                                unsigned short* __restrict__ Pb) {
    const int i8 = blockIdx.x * 256 + threadIdx.x;
    const float4 v1 = *(const float4*)(pts + (size_t)i8 * 8);
    const float4 v2 = *(const float4*)(pts + (size_t)i8 * 8 + 4);
    uint4 wv;
    wv.x = pack2(v1.x, v1.y); wv.y = pack2(v1.z, v1.w);
    wv.z = pack2(v2.x, v2.y); wv.w = pack2(v2.z, v2.w);
    *(uint4*)(Pb + (size_t)i8 * 8) = wv;
}

// Expand q_coefs (n_mono,64) -> W[k][e][d] (bf16, d contiguous). norm2 partials
// as plain per-block stores (no atomics — 64-lane atomicAdd on 2 cache lines
// serialized ~65K RMWs and cost ~110 us in rounds 3-4).
__global__ __launch_bounds__(256, 4)
void hsq_expand_kernel(const float* __restrict__ qc,
                       unsigned short* __restrict__ W,
                       float* __restrict__ npart) {
    const int e    = blockIdx.x;          // 0..511
    const int dblk = blockIdx.y;          // 0..3
    const int pb   = blockIdx.y * 512 + blockIdx.x;   // 0..2047
    const int wid  = threadIdx.x >> 6;
    const int k    = threadIdx.x & 63;    // lane = quadric index
    const int d0   = dblk * 128 + wid * 32;

    __shared__ unsigned short tv[64 * 136];
    __shared__ float part[4][64];

    float v[32];
#pragma unroll
    for (int s = 0; s < 32; ++s) {
        const int d = d0 + s;
        const int i = d < e ? d : e;
        const int j = d < e ? e : d;
        const int idx = i * DIM - ((i * (i - 1)) >> 1) + (j - i);
        v[s] = qc[(size_t)idx * NQ + k];
    }

    float nacc = 0.0f;
#pragma unroll
    for (int s = 0; s < 32; ++s)
        if (d0 + s >= e) nacc += v[s] * v[s];

#pragma unroll
    for (int t = 0; t < 4; ++t) {
        float sc[8];
#pragma unroll
        for (int q = 0; q < 8; ++q) {
            const int d = d0 + t * 8 + q;
            sc[q] = v[t * 8 + q] * ((d == e) ? 2.0f : 1.41421356237309515f);
        }
        uint4 w;
        w.x = pack2(sc[0], sc[1]); w.y = pack2(sc[2], sc[3]);
        w.z = pack2(sc[4], sc[5]); w.w = pack2(sc[6], sc[7]);
        *(uint4*)&tv[k * 136 + wid * 32 + t * 8] = w;
    }
    part[wid][k] = nacc;
    __syncthreads();

#pragma unroll
    for (int r = 0; r < 4; ++r) {
        const int kk = r * 16 + (threadIdx.x >> 4);
        const int u  = threadIdx.x & 15;
        const uint4 w = *(const uint4*)&tv[kk * 136 + u * 8];
        *(uint4*)(W + ((size_t)(kk * DIM + e)) * DIM + dblk * 128 + u * 8) = w;
    }
    if (threadIdx.x < 64) {
        npart[(size_t)k * 2048 + pb] =
            part[0][k] + part[1][k] + part[2][k] + part[3][k];
    }
}

// m97-style GEMM, BK=32. Occupancy history: 2 blk/CU spill-free = 135 us (R5);
// 4 blk/CU = 128-reg budget, acc(64 AGPR) + frags(32) + addr > budget ->
// 76-146 MB scratch spills (R6/R7). This round: 3 blk/CU (~170-reg budget,
// ~136 needed — spill-free) via __launch_bounds__(256,3).
__global__ __launch_bounds__(256, 3)
void hsq_gemm_kernel(const unsigned short* __restrict__ Pb,
                     const unsigned short* __restrict__ W,
                     const float* __restrict__ l_coefs,
                     float2* __restrict__ part) {
    // XCD swizzle: each XCD owns 8 k's; concurrent W set ~= 1-2 slabs (<=1 MB).
    const int bid = blockIdx.x;
    const int xcd = bid & 7;
    const int loc = bid >> 3;                 // 0..511
    const int k   = xcd * 8 + (loc >> 6);     // 0..63
    const int rem = loc & 63;
    const int eb  = rem >> 4;                 // 0..3 (e-range of 128)
    const int m0  = (rem & 15) * 128;         // batch-tile base

    const int tid   = threadIdx.x;
    const int w     = tid >> 6;
    const int lane  = tid & 63;
    const int mhalf = w >> 1, nhalf = w & 1;
    const int c     = lane & 15;              // MFMA col
    const int quad  = lane >> 4;              // MFMA k-chunk / D row-block

    __shared__ unsigned short Ab[2][128 * 32];   // 2 x 8 KB
    __shared__ unsigned short Bb[2][128 * 32];   // 2 x 8 KB
    __shared__ float red[2][128][2];             // 2 KB

    const unsigned short* Wk = W + (size_t)k * DIM * DIM + (size_t)eb * 128 * DIM;

#define STAGE(buf_, it_) do {                                                   \
    const int lr_  = lane >> 2;                                                 \
    const int gch_ = (lane & 3) ^ ((lane >> 3) & 3);                            \
    _Pragma("unroll")                                                           \
    for (int i_ = 0; i_ < 2; ++i_) {                                            \
        const int rb_  = w * 32 + i_ * 16;                                      \
        const int row_ = rb_ + lr_;                                             \
        __builtin_amdgcn_global_load_lds(                                       \
            (const __attribute__((address_space(1))) unsigned int*)             \
                (Pb + (size_t)(m0 + row_) * DIM + (it_) * 32 + gch_ * 8),       \
            (__attribute__((address_space(3))) unsigned int*)                   \
                &Ab[buf_][rb_ * 32], 16, 0, 0);                                 \
        __builtin_amdgcn_global_load_lds(                                       \
            (const __attribute__((address_space(1))) unsigned int*)             \
                (Wk + (size_t)row_ * DIM + (it_) * 32 + gch_ * 8),              \
            (__attribute__((address_space(3))) unsigned int*)                   \
                &Bb[buf_][rb_ * 32], 16, 0, 0);                                 \
    }                                                                           \
} while (0)

    floatx4 acc[4][4];
#pragma unroll
    for (int mt = 0; mt < 4; ++mt)
#pragma unroll
        for (int nt = 0; nt < 4; ++nt)
            acc[mt][nt] = (floatx4){0.f, 0.f, 0.f, 0.f};

    STAGE(0, 0);
    __syncthreads();

    for (int it = 0; it < 16; ++it) {
        const int buf = it & 1;
        if (it < 15) STAGE(buf ^ 1, it + 1);

        bf16x8 af[4], bfr[4];
#pragma unroll
        for (int mt = 0; mt < 4; ++mt) {
            const int row  = mhalf * 64 + mt * 16 + c;
            const int slot = quad ^ ((row >> 1) & 3);
            af[mt] = *(const bf16x8*)&Ab[buf][row * 32 + slot * 8];
        }
#pragma unroll
        for (int nt = 0; nt < 4; ++nt) {
            const int er   = nhalf * 64 + nt * 16 + c;
            const int slot = quad ^ ((er >> 1) & 3);
            bfr[nt] = *(const bf16x8*)&Bb[buf][er * 32 + slot * 8];
        }
#pragma unroll
        for (int mt = 0; mt < 4; ++mt)
#pragma unroll
            for (int nt = 0; nt < 4; ++nt)
                acc[mt][nt] = __builtin_amdgcn_mfma_f32_16x16x32_bf16(
                    af[mt], bfr[nt], acc[mt][nt], 0, 0, 0);
        __syncthreads();
    }
#undef STAGE

    // ---- Epilogue: pv = sum_e p*(0.5g+l), pg = sum_e (g+l)^2 over this eb ----
    // p and l loaded here (post-K-loop — keeps them out of the K-loop's
    // register peak). Pb/l_coefs are L2-hot.
    float lcv[4];
#pragma unroll
    for (int nt = 0; nt < 4; ++nt)
        lcv[nt] = l_coefs[(eb * 128 + nhalf * 64 + nt * 16 + c) * NQ + k];

    const unsigned short* Pe = Pb + (size_t)(m0 + mhalf * 64) * DIM
                                  + eb * 128 + nhalf * 64 + c;
#pragma unroll
    for (int mt = 0; mt < 4; ++mt)
#pragma unroll
        for (int r = 0; r < 4; ++r) {
            const unsigned short* Prow = Pe + (size_t)(mt * 16 + quad * 4 + r) * DIM;
            float pv = 0.f, pg = 0.f;
#pragma unroll
            for (int nt = 0; nt < 4; ++nt) {
                const float g = acc[mt][nt][r];
                const float l = lcv[nt];
                pv += bf2f(Prow[nt * 16]) * (0.5f * g + l);
                const float gq = g + l;
                pg += gq * gq;
            }
#pragma unroll
            for (int off = 1; off < 16; off <<= 1) {
                pv += __shfl_xor(pv, off);
                pg += __shfl_xor(pg, off);
            }
            if (c == 0) {
                const int row = mhalf * 64 + mt * 16 + quad * 4 + r;
                red[nhalf][row][0] = pv;
                red[nhalf][row][1] = pg;
            }
        }
    __syncthreads();

    if (tid < 128) {
        const float pv = red[0][tid][0] + red[1][tid][0];
        const float pg = red[0][tid][1] + red[1][tid][1];
        part[((size_t)(eb * NQ + k)) * BATCH + m0 + tid] = make_float2(pv, pg);
    }
}

// Final: block per k. Reduces npart[k][*] -> norm2 in-block, then combines the
// 4 e-range partials into scores (coalesced reads).
__global__ void hsq_final_kernel(const float2* __restrict__ part,
                                 const float* __restrict__ npart,
                                 const float* __restrict__ free_coefs,
                                 float* __restrict__ out) {
    const int k = blockIdx.x;
    const int t = threadIdx.x;
    __shared__ float ws[4];

    const float4* src = (const float4*)(npart + (size_t)k * 2048);
    const float4 a = src[t * 2], b = src[t * 2 + 1];
    float s = a.x + a.y + a.z + a.w + b.x + b.y + b.z + b.w;
#pragma unroll
    for (int off = 1; off < 64; off <<= 1) s += __shfl_xor(s, off);
    if ((t & 63) == 0) ws[t >> 6] = s;
    __syncthreads();
    const float nrm = sqrtf(ws[0] + ws[1] + ws[2] + ws[3]);
    const float fc  = free_coefs[k];

#pragma unroll
    for (int i = 0; i < 8; ++i) {
        const int bidx = i * 256 + t;
        float pv = 0.f, pg = 0.f;
#pragma unroll
        for (int eb = 0; eb < 4; ++eb) {
            const float2 p = part[((size_t)(eb * NQ + k)) * BATCH + bidx];
            pv += p.x; pg += p.y;
        }
        const float vals = fabsf(pv + fc);
        out[(size_t)bidx * NQ + k] = (sqrtf(0.25f * pg + vals * nrm) - 0.5f * sqrtf(pg)) / nrm;
    }
}

extern "C" void kernel_launch(void* const* d_in, const int* in_sizes, int n_in,
                              void* d_out, int out_size, void* d_ws, size_t ws_size,
                              hipStream_t stream) {
    const float* points     = (const float*)d_in[0];  // (2048, 512)
    const float* q_coefs    = (const float*)d_in[1];  // (131328, 64)
    const float* l_coefs    = (const float*)d_in[2];  // (512, 64)
    const float* free_coefs = (const float*)d_in[3];  // (1, 64)
    float* out = (float*)d_out;                       // (2048, 64)

    char* ws = (char*)d_ws;
    unsigned short* W  = (unsigned short*)ws;                              // 32 MiB
    unsigned short* Pb = (unsigned short*)(ws + 33554432);                 // 2 MiB
    float2*         part  = (float2*)(ws + 35651584);                      // 4 MiB
    float*          npart = (float*)(ws + 39845888);                       // 512 KiB

    hsq_pack_kernel<<<dim3(BATCH * DIM / 8 / 256), 256, 0, stream>>>(points, Pb);
    hsq_expand_kernel<<<dim3(DIM, 4), 256, 0, stream>>>(q_coefs, W, npart);
    hsq_gemm_kernel<<<dim3(NQ * 64), 256, 0, stream>>>(Pb, W, l_coefs, part);
    hsq_final_kernel<<<dim3(NQ), 256, 0, stream>>>(part, npart, free_coefs, out);
}